// Round 1
// baseline (1143.230 us; speedup 1.0000x reference)
//
#include <hip/hip_runtime.h>
#include <hip/hip_bf16.h>

#define B_ 4
#define N_ 10000
#define E_ 80000
#define D_ 256

static __device__ __forceinline__ float wave_sum(float v){
  #pragma unroll
  for(int o=32;o>0;o>>=1) v += __shfl_xor(v, o);
  return v;
}

// blockDim.x == 256 (4 waves). red must be >=4 floats of shared mem.
static __device__ __forceinline__ float block_sum(float v, float* red){
  v = wave_sum(v);
  int w = threadIdx.x >> 6;
  if((threadIdx.x & 63) == 0) red[w] = v;
  __syncthreads();
  float r = (red[0] + red[1]) + (red[2] + red[3]);
  __syncthreads();
  return r;
}

// ---------------- node input projection: h = [nf | gf] @ W + b ----------------
// 16 node-rows per block, 256 threads (thread = output channel).
__global__ __launch_bounds__(256) void k_node_in(
    const float* __restrict__ nf, const float* __restrict__ gf,
    const float* __restrict__ W, const float* __restrict__ bias,
    float* __restrict__ h){
  __shared__ float in_s[16][96];
  int base = blockIdx.x * 16;
  int tid = threadIdx.x;
  for(int idx = tid; idx < 16*96; idx += 256){
    int i = idx / 96, k = idx - i*96;
    int row = base + i;
    int b = row / N_;
    float v = (k < 64) ? nf[(size_t)row*64 + k] : gf[b*32 + (k-64)];
    in_s[i][k] = v;
  }
  __syncthreads();
  int c = tid;
  float acc[16];
  #pragma unroll
  for(int i=0;i<16;i++) acc[i]=0.f;
  for(int k=0;k<96;k+=4){
    float w0 = W[(k+0)*D_+c], w1 = W[(k+1)*D_+c];
    float w2 = W[(k+2)*D_+c], w3 = W[(k+3)*D_+c];
    #pragma unroll
    for(int i=0;i<16;i++){
      float4 a = *reinterpret_cast<const float4*>(&in_s[i][k]);
      acc[i] += a.x*w0 + a.y*w1 + a.z*w2 + a.w*w3;
    }
  }
  float bc = bias[c];
  #pragma unroll
  for(int i=0;i<16;i++) h[(size_t)(base+i)*D_ + c] = acc[i] + bc;
}

// ---------------- CSR build ----------------
__global__ __launch_bounds__(256) void k_hist(
    const int* __restrict__ el, const int* __restrict__ emask,
    int* __restrict__ counts){
  int e = blockIdx.x*256 + threadIdx.x;
  if(e >= B_*E_) return;
  if(emask[e]){
    int b = e / E_;
    int r = el[(size_t)e*2 + 1];
    atomicAdd(&counts[b*N_ + r], 1);
  }
}

__global__ __launch_bounds__(1024) void k_scan(
    const int* __restrict__ counts, int* __restrict__ offsets){
  __shared__ int sm[1024];
  __shared__ int carry_s;
  int tid = threadIdx.x;
  if(tid==0) carry_s = 0;
  __syncthreads();
  for(int base=0; base<B_*N_; base+=1024){
    int idx = base + tid;
    int x = (idx < B_*N_) ? counts[idx] : 0;
    sm[tid] = x;
    __syncthreads();
    for(int off=1; off<1024; off<<=1){
      int v = (tid >= off) ? sm[tid-off] : 0;
      __syncthreads();
      sm[tid] += v;
      __syncthreads();
    }
    int incl = sm[tid];
    int carry = carry_s;
    if(idx < B_*N_) offsets[idx] = carry + incl - x;
    __syncthreads();
    if(tid == 1023) carry_s = carry + incl;
    __syncthreads();
  }
  if(tid==0) offsets[B_*N_] = carry_s;
}

__global__ __launch_bounds__(256) void k_fill(
    const int* __restrict__ el, const int* __restrict__ emask,
    const int* __restrict__ offsets, int* __restrict__ cursor,
    int* __restrict__ s_edge, int* __restrict__ s_send){
  int e = blockIdx.x*256 + threadIdx.x;
  if(e >= B_*E_) return;
  if(emask[e]){
    int b = e / E_;
    int s = el[(size_t)e*2], r = el[(size_t)e*2 + 1];
    int bn = b*N_ + r;
    int pos = offsets[bn] + atomicAdd(&cursor[bn], 1);
    s_edge[pos] = e;
    s_send[pos] = b*N_ + s;
  }
}

// ---------------- fused edge proj + LN + relu + receiver segment-sum ----------------
// one block per (b, node); threads = 256 output channels.
__global__ __launch_bounds__(256) void k_se(
    const float* __restrict__ ef, const float* __restrict__ W,
    const float* __restrict__ bias, const float* __restrict__ lns,
    const float* __restrict__ lnb, const int* __restrict__ offsets,
    const int* __restrict__ s_edge, float* __restrict__ Se){
  __shared__ float ef_s[16];
  __shared__ float red[4];
  int bn = blockIdx.x;
  int c = threadIdx.x;
  int beg = offsets[bn], end = offsets[bn+1];
  float wcol[16];
  #pragma unroll
  for(int k=0;k<16;k++) wcol[k] = W[k*D_ + c];
  float bc = bias[c], sc = lns[c], bb = lnb[c];
  float acc = 0.f;
  for(int slot=beg; slot<end; ++slot){
    int e = s_edge[slot];
    if(c < 16) ef_s[c] = ef[(size_t)e*16 + c];
    __syncthreads();
    float t = bc;
    #pragma unroll
    for(int k=0;k<16;k++) t += ef_s[k]*wcol[k];
    float s1 = block_sum(t, red);
    float mean = s1 * (1.f/256.f);
    float d = t - mean;
    float s2 = block_sum(d*d, red);
    float v = d * rsqrtf(s2*(1.f/256.f) + 1e-6f) * sc + bb;
    acc += fmaxf(v, 0.f);
    __syncthreads();
  }
  Se[(size_t)bn*D_ + c] = acc;
}

// ---------------- LN + relu (wave per row, 4 rows/block) ----------------
__global__ __launch_bounds__(256) void k_ln_relu(
    const float* __restrict__ h, const float* __restrict__ s,
    const float* __restrict__ b, float* __restrict__ hn){
  int row = blockIdx.x*4 + (threadIdx.x>>6);
  int lane = threadIdx.x & 63;
  int c = lane*4;
  float4 x = *reinterpret_cast<const float4*>(&h[(size_t)row*D_ + c]);
  float sum = x.x+x.y+x.z+x.w;
  float sq = x.x*x.x+x.y*x.y+x.z*x.z+x.w*x.w;
  #pragma unroll
  for(int o=32;o>0;o>>=1){ sum += __shfl_xor(sum,o); sq += __shfl_xor(sq,o); }
  float mean = sum*(1.f/256.f);
  float var = sq*(1.f/256.f) - mean*mean;
  float rs = rsqrtf(var + 1e-6f);
  float4 s4 = *reinterpret_cast<const float4*>(&s[c]);
  float4 b4 = *reinterpret_cast<const float4*>(&b[c]);
  float4 o4;
  o4.x = fmaxf((x.x-mean)*rs*s4.x + b4.x, 0.f);
  o4.y = fmaxf((x.y-mean)*rs*s4.y + b4.y, 0.f);
  o4.z = fmaxf((x.z-mean)*rs*s4.z + b4.z, 0.f);
  o4.w = fmaxf((x.w-mean)*rs*s4.w + b4.w, 0.f);
  *reinterpret_cast<float4*>(&hn[(size_t)row*D_ + c]) = o4;
}

// ---------------- gather-sum of sender rows per receiver (wave per node) ----------------
__global__ __launch_bounds__(256) void k_agg(
    const float* __restrict__ hn, const int* __restrict__ offsets,
    const int* __restrict__ s_send, float* __restrict__ A){
  int bn = blockIdx.x*4 + (threadIdx.x>>6);
  int lane = threadIdx.x & 63;
  int beg = offsets[bn], end = offsets[bn+1];
  float4 acc = {0.f,0.f,0.f,0.f};
  for(int slot=beg; slot<end; ++slot){
    int sr = s_send[slot];
    float4 v = *reinterpret_cast<const float4*>(&hn[(size_t)sr*D_ + lane*4]);
    acc.x += v.x; acc.y += v.y; acc.z += v.z; acc.w += v.w;
  }
  *reinterpret_cast<float4*>(&A[(size_t)bn*D_ + lane*4]) = acc;
}

// ---------------- GEMM: hout = hn + (concat(A,Se) @ W + cnt*bias)/deg ----------------
// M=40000, K=512, N=256. 64x128 tile per block; thread micro-tile 4x8.
__global__ __launch_bounds__(256) void k_gemm(
    const float* __restrict__ Abuf, const float* __restrict__ Se,
    const float* __restrict__ W, const float* __restrict__ bias,
    const int* __restrict__ counts, const float* __restrict__ hn,
    float* __restrict__ hout){
  __shared__ float A_s[16][64];
  __shared__ float B_s[16][128];
  int bid = blockIdx.x;
  int row0 = (bid >> 1) * 64;
  int col0 = (bid & 1) * 128;
  int tid = threadIdx.x;
  int tx = tid >> 4;            // 0..15 col group (8 cols)
  int ty = tid & 15;            // 0..15 row group (4 rows)
  int lm = tid & 63, lk = tid >> 6;         // A-tile load
  int lc = (tid & 31) * 4, lr = tid >> 5;   // B-tile load
  float acc[4][8];
  #pragma unroll
  for(int r=0;r<4;r++)
    #pragma unroll
    for(int j=0;j<8;j++) acc[r][j]=0.f;
  for(int kk=0; kk<32; ++kk){
    int k0 = kk*16;
    const float* asrc = (k0 < 256) ? (Abuf + k0) : (Se + (k0 - 256));
    float4 av  = *reinterpret_cast<const float4*>(&asrc[(size_t)(row0+lm)*D_ + lk*4]);
    float4 bv0 = *reinterpret_cast<const float4*>(&W[(size_t)(k0+lr)*D_ + col0 + lc]);
    float4 bv1 = *reinterpret_cast<const float4*>(&W[(size_t)(k0+lr+8)*D_ + col0 + lc]);
    __syncthreads();
    A_s[lk*4+0][lm] = av.x;
    A_s[lk*4+1][lm] = av.y;
    A_s[lk*4+2][lm] = av.z;
    A_s[lk*4+3][lm] = av.w;
    *reinterpret_cast<float4*>(&B_s[lr  ][lc]) = bv0;
    *reinterpret_cast<float4*>(&B_s[lr+8][lc]) = bv1;
    __syncthreads();
    #pragma unroll
    for(int k=0;k<16;k++){
      float4 a  = *reinterpret_cast<const float4*>(&A_s[k][ty*4]);
      float4 b0 = *reinterpret_cast<const float4*>(&B_s[k][tx*8]);
      float4 b1 = *reinterpret_cast<const float4*>(&B_s[k][tx*8+4]);
      float ar[4] = {a.x,a.y,a.z,a.w};
      float br[8] = {b0.x,b0.y,b0.z,b0.w,b1.x,b1.y,b1.z,b1.w};
      #pragma unroll
      for(int r=0;r<4;r++)
        #pragma unroll
        for(int j=0;j<8;j++) acc[r][j] += ar[r]*br[j];
    }
  }
  #pragma unroll
  for(int r=0;r<4;r++){
    int row = row0 + ty*4 + r;
    float cf = (float)counts[row];
    float inv = 1.0f / fmaxf(cf, 1.0f);
    #pragma unroll
    for(int j=0;j<8;j++){
      int c = col0 + tx*8 + j;
      hout[(size_t)row*D_ + c] = hn[(size_t)row*D_ + c] + (acc[r][j] + cf*bias[c]) * inv;
    }
  }
}

// ---------------- attention prep: q_in, q=LN, Q=q@Wq+bq, fold into Wk ----------------
__global__ __launch_bounds__(256) void k_qprep(
    const float* __restrict__ h, const int* __restrict__ agent,
    const float* __restrict__ lnq_s, const float* __restrict__ lnq_b,
    const float* __restrict__ Wq, const float* __restrict__ bq,
    const float* __restrict__ Wk, const float* __restrict__ bk,
    float* __restrict__ q_in, float* __restrict__ Wq_eff,
    float* __restrict__ qconst){
  __shared__ float q_s[256];
  __shared__ float Q_s[256];
  __shared__ float red[4];
  int b = blockIdx.x, c = threadIdx.x;
  size_t row = (size_t)(b*N_ + agent[b]);
  float x = h[row*D_ + c];
  q_in[b*D_ + c] = x;
  float s1 = block_sum(x, red);
  float mean = s1*(1.f/256.f);
  float d = x - mean;
  float s2 = block_sum(d*d, red);
  float q = d * rsqrtf(s2*(1.f/256.f) + 1e-6f) * lnq_s[c] + lnq_b[c];
  q_s[c] = q;
  __syncthreads();
  float acc = bq[c];
  for(int k=0;k<256;k++) acc += q_s[k]*Wq[k*D_ + c];
  Q_s[c] = acc;
  __syncthreads();
  const float scale = 0.17677669529663687f; // 1/sqrt(32)
  for(int idx=c; idx<2048; idx+=256){
    int hh = idx >> 8, dd = idx & 255;
    const float4* wk4 = reinterpret_cast<const float4*>(&Wk[(size_t)dd*D_ + hh*32]);
    const float4* q4  = reinterpret_cast<const float4*>(&Q_s[hh*32]);
    float t = 0.f;
    #pragma unroll
    for(int k4=0;k4<8;k4++){
      float4 w = wk4[k4]; float4 qq = q4[k4];
      t += w.x*qq.x + w.y*qq.y + w.z*qq.z + w.w*qq.w;
    }
    Wq_eff[b*2048 + hh*256 + dd] = t*scale;
  }
  if(c < 8){
    float t = 0.f;
    for(int dh=0; dh<32; dh++) t += Q_s[c*32+dh]*bk[c*32+dh];
    qconst[b*8 + c] = t*scale;
  }
}

// ---------------- k=LN(h) + masked scores (wave per node, 4 nodes/block) ----------------
__global__ __launch_bounds__(256) void k_scores(
    const float* __restrict__ h, const float* __restrict__ lnk_s,
    const float* __restrict__ lnk_b, const float* __restrict__ Wq_eff,
    const float* __restrict__ qconst, const int* __restrict__ nmask,
    float* __restrict__ kbuf, float* __restrict__ scores){
  __shared__ float wq_s[2048];
  int row0 = blockIdx.x * 4;
  int b = row0 / N_;
  for(int i=threadIdx.x; i<2048; i+=256) wq_s[i] = Wq_eff[b*2048 + i];
  __syncthreads();
  int wave = threadIdx.x >> 6, lane = threadIdx.x & 63;
  int row = row0 + wave;
  int n = row - b*N_;
  int c = lane*4;
  float4 x = *reinterpret_cast<const float4*>(&h[(size_t)row*D_ + c]);
  float sum = x.x+x.y+x.z+x.w;
  float sq = x.x*x.x+x.y*x.y+x.z*x.z+x.w*x.w;
  #pragma unroll
  for(int o=32;o>0;o>>=1){ sum += __shfl_xor(sum,o); sq += __shfl_xor(sq,o); }
  float mean = sum*(1.f/256.f);
  float var = sq*(1.f/256.f) - mean*mean;
  float rs = rsqrtf(var + 1e-6f);
  float4 s4 = *reinterpret_cast<const float4*>(&lnk_s[c]);
  float4 b4 = *reinterpret_cast<const float4*>(&lnk_b[c]);
  float4 kv;
  kv.x = (x.x-mean)*rs*s4.x + b4.x;
  kv.y = (x.y-mean)*rs*s4.y + b4.y;
  kv.z = (x.z-mean)*rs*s4.z + b4.z;
  kv.w = (x.w-mean)*rs*s4.w + b4.w;
  *reinterpret_cast<float4*>(&kbuf[(size_t)row*D_ + c]) = kv;
  bool valid = nmask[row] != 0;
  #pragma unroll
  for(int hh=0; hh<8; hh++){
    float4 w = *reinterpret_cast<const float4*>(&wq_s[hh*256 + c]);
    float p = kv.x*w.x + kv.y*w.y + kv.z*w.z + kv.w*w.w;
    p = wave_sum(p);
    if(lane==0) scores[(size_t)(b*8+hh)*N_ + n] = valid ? (p + qconst[b*8+hh]) : -1e9f;
  }
}

// ---------------- softmax over N per (b,h); stores exp(s-m), invsum ----------------
__global__ __launch_bounds__(256) void k_softmax(
    float* __restrict__ scores, float* __restrict__ invsum){
  __shared__ float red[4];
  int bh = blockIdx.x; int tid = threadIdx.x;
  float m = -3e38f;
  for(int n=tid; n<N_; n+=256) m = fmaxf(m, scores[(size_t)bh*N_ + n]);
  #pragma unroll
  for(int o=32;o>0;o>>=1) m = fmaxf(m, __shfl_xor(m,o));
  if((tid&63)==0) red[tid>>6] = m;
  __syncthreads();
  m = fmaxf(fmaxf(red[0],red[1]), fmaxf(red[2],red[3]));
  __syncthreads();
  float s = 0.f;
  for(int n=tid; n<N_; n+=256){
    float p = __expf(scores[(size_t)bh*N_ + n] - m);
    scores[(size_t)bh*N_ + n] = p;
    s += p;
  }
  s = block_sum(s, red);
  if(tid==0) invsum[bh] = 1.f/s;
}

// ---------------- kbar[b,h,:] = invsum * sum_n p[b,h,n]*k[b,n,:] ----------------
__global__ __launch_bounds__(256) void k_kbar(
    const float* __restrict__ kbuf, const float* __restrict__ scores,
    const float* __restrict__ invsum, float* __restrict__ kbar){
  __shared__ float p_s[8][252];
  int b = blockIdx.x / 40;
  int n0 = (blockIdx.x % 40) * 250;
  for(int i=threadIdx.x; i<8*250; i+=256){
    int hh = i/250, nn = i - hh*250;
    p_s[hh][nn] = scores[(size_t)(b*8+hh)*N_ + n0 + nn];
  }
  __syncthreads();
  int c = threadIdx.x;
  float acc[8] = {0.f,0.f,0.f,0.f,0.f,0.f,0.f,0.f};
  for(int nn=0; nn<250; ++nn){
    float kv = kbuf[(size_t)(b*N_ + n0 + nn)*D_ + c];
    #pragma unroll
    for(int hh=0;hh<8;hh++) acc[hh] += p_s[hh][nn]*kv;
  }
  #pragma unroll
  for(int hh=0;hh<8;hh++)
    atomicAdd(&kbar[(b*8+hh)*D_ + c], acc[hh]*invsum[b*8+hh]);
}

// ---------------- o = kbar@Wv + bv ; x = relu(LN(q_in + o@Wo + bo)) ----------------
__global__ __launch_bounds__(256) void k_final(
    const float* __restrict__ kbar, const float* __restrict__ Wv,
    const float* __restrict__ bv, const float* __restrict__ Wo,
    const float* __restrict__ bo, const float* __restrict__ q_in,
    const float* __restrict__ lnf_s, const float* __restrict__ lnf_b,
    float* __restrict__ out){
  __shared__ float kb_s[2048];
  __shared__ float o_s[256];
  __shared__ float red[4];
  int b = blockIdx.x, c = threadIdx.x;
  for(int i=c; i<2048; i+=256) kb_s[i] = kbar[b*2048 + i];
  __syncthreads();
  int hh = c >> 5;
  float o = bv[c];
  for(int d=0; d<256; d++) o += kb_s[hh*256 + d]*Wv[(size_t)d*D_ + c];
  o_s[c] = o;
  __syncthreads();
  float y = bo[c] + q_in[b*D_ + c];
  for(int d=0; d<256; d++) y += o_s[d]*Wo[(size_t)d*D_ + c];
  float s1 = block_sum(y, red);
  float mean = s1*(1.f/256.f);
  float dd = y - mean;
  float s2 = block_sum(dd*dd, red);
  float v = dd * rsqrtf(s2*(1.f/256.f) + 1e-6f) * lnf_s[c] + lnf_b[c];
  out[b*D_ + c] = fmaxf(v, 0.f);
}

extern "C" void kernel_launch(void* const* d_in, const int* in_sizes, int n_in,
                              void* d_out, int out_size, void* d_ws, size_t ws_size,
                              hipStream_t stream){
  const float* nf    = (const float*)d_in[0];
  const float* ef    = (const float*)d_in[1];
  const float* gf    = (const float*)d_in[2];
  const int*   el    = (const int*)d_in[3];
  const int*   emask = (const int*)d_in[4];
  const int*   nmask = (const int*)d_in[5];
  const int*   agent = (const int*)d_in[6];
  const float* W_node = (const float*)d_in[7];
  const float* b_node = (const float*)d_in[8];
  const float* W_edge = (const float*)d_in[9];
  const float* b_edge = (const float*)d_in[10];
  const float* ln_e_s = (const float*)d_in[11];
  const float* ln_e_b = (const float*)d_in[12];
  const float* gcn_W  = (const float*)d_in[13];
  const float* gcn_b  = (const float*)d_in[14];
  const float* ln_s   = (const float*)d_in[15];
  const float* ln_b   = (const float*)d_in[16];
  const float* lnq_s  = (const float*)d_in[17];
  const float* lnq_b  = (const float*)d_in[18];
  const float* lnk_s  = (const float*)d_in[19];
  const float* lnk_b  = (const float*)d_in[20];
  const float* Wq = (const float*)d_in[21];
  const float* bq = (const float*)d_in[22];
  const float* Wk = (const float*)d_in[23];
  const float* bk = (const float*)d_in[24];
  const float* Wv = (const float*)d_in[25];
  const float* bv = (const float*)d_in[26];
  const float* Wo = (const float*)d_in[27];
  const float* bo = (const float*)d_in[28];
  const float* lnf_s = (const float*)d_in[29];
  const float* lnf_b = (const float*)d_in[30];
  float* out = (float*)d_out;

  const size_t ND = (size_t)B_*N_*D_;
  float* fw     = (float*)d_ws;
  float* h_buf  = fw;
  float* hn_buf = h_buf  + ND;
  float* A_buf  = hn_buf + ND;          // reused as kbuf for attention
  float* Se_buf = A_buf  + ND;
  float* scores = Se_buf + ND;          // B*8*N
  float* q_in   = scores + (size_t)B_*8*N_;
  float* Wq_eff = q_in   + B_*D_;
  float* qconst = Wq_eff + B_*8*D_;
  float* invsum = qconst + B_*8;
  float* kbar   = invsum + B_*8;
  int* counts  = (int*)(kbar + B_*8*D_);
  int* cursor  = counts + B_*N_;
  int* offsets = cursor + B_*N_;
  int* s_edge  = offsets + (B_*N_+1);
  int* s_send  = s_edge + B_*E_;

  hipMemsetAsync(counts, 0, sizeof(int)*(size_t)2*B_*N_, stream);
  hipMemsetAsync(kbar, 0, sizeof(float)*(size_t)B_*8*D_, stream);

  k_node_in<<<B_*N_/16, 256, 0, stream>>>(nf, gf, W_node, b_node, h_buf);
  k_hist<<<B_*E_/256, 256, 0, stream>>>(el, emask, counts);
  k_scan<<<1, 1024, 0, stream>>>(counts, offsets);
  k_fill<<<B_*E_/256, 256, 0, stream>>>(el, emask, offsets, cursor, s_edge, s_send);
  k_se<<<B_*N_, 256, 0, stream>>>(ef, W_edge, b_edge, ln_e_s, ln_e_b, offsets, s_edge, Se_buf);

  for(int i=0;i<3;i++){
    k_ln_relu<<<B_*N_/4, 256, 0, stream>>>(h_buf, ln_s + i*D_, ln_b + i*D_, hn_buf);
    k_agg<<<B_*N_/4, 256, 0, stream>>>(hn_buf, offsets, s_send, A_buf);
    k_gemm<<<(B_*N_/64)*2, 256, 0, stream>>>(A_buf, Se_buf, gcn_W + (size_t)i*512*D_,
                                             gcn_b + i*D_, counts, hn_buf, h_buf);
  }

  k_qprep<<<B_, 256, 0, stream>>>(h_buf, agent, lnq_s, lnq_b, Wq, bq, Wk, bk,
                                  q_in, Wq_eff, qconst);
  k_scores<<<B_*N_/4, 256, 0, stream>>>(h_buf, lnk_s, lnk_b, Wq_eff, qconst, nmask,
                                        A_buf, scores);
  k_softmax<<<B_*8, 256, 0, stream>>>(scores, invsum);
  k_kbar<<<B_*40, 256, 0, stream>>>(A_buf, scores, invsum, kbar);
  k_final<<<B_, 256, 0, stream>>>(kbar, Wv, bv, Wo, bo, q_in, lnf_s, lnf_b, out);
}